// Round 2
// baseline (7664.613 us; speedup 1.0000x reference)
//
#include <hip/hip_runtime.h>
#include <hip/hip_cooperative_groups.h>
#include <math.h>

namespace cg = cooperative_groups;

#define HH 4096          // 64*64
#define NSLOT 520        // Phi snapshots (complex, 8192 floats each)
#define MAXATT 512

// ---- ws layout (float offsets) ----
#define OFF_A     0                              // A^0..A^7: 8*4096
#define OFF_PHI   (32768)                        // NSLOT * 8192 (re|im)
#define OFF_RE    (OFF_PHI + NSLOT*8192)         // Rre|Rim|Ere|Eim: 4*4096
#define OFF_EY    (OFF_RE + 4*HH)                // EYre|EYim: 2*4096
#define OFF_Y     (OFF_EY + 2*HH)                // 2 bufs x (u 262144 | v 262144)
#define OFF_PART  (OFF_Y + 1048576)              // 64 partials
#define OFF_CTRL  (OFF_PART + 64)                // 32 scalars
#define OFF_REC   (OFF_CTRL + 32)                // 128 x 4 (step, tau, h, pad)
#define OFF_THETA (OFF_REC + 512)                // 128 x 4096 (Re Theta_t)
// total ~5.9M floats ~22.6 MB

struct Coefs { float r[8], e[8], pa[8], pb[8], pc[8]; };

// ---------------------------------------------------------------------------
// Host: derive dopri5 polynomial coefficients from the (jax/torchdiffeq)
// tableau. R = step map, E = error map, M = midpoint, Pa/Pb/Pc = interp
// polynomial combos:  y(tau) = Phi*(tau^4 Pa + tau^3 Pb + tau^2 Pc + tau*W + 1)
// Checks: sum(c_mid)=0.5, sum(b_hat)=1, Pa+Pb+Pc+W+1 == R at tau=1.
// ---------------------------------------------------------------------------
static Coefs make_coefs() {
    static const double beta[6][6] = {
        {1./5, 0, 0, 0, 0, 0},
        {3./40, 9./40, 0, 0, 0, 0},
        {44./45, -56./15, 32./9, 0, 0, 0},
        {19372./6561, -25360./2187, 64448./6561, -212./729, 0, 0},
        {9017./3168, -355./33, 46732./5247, 49./176, -5103./18656, 0},
        {35./384, 0., 500./1113, 125./192, -2187./6784, 11./84}};
    static const double c_sol[7] = {35./384, 0., 500./1113, 125./192,
                                    -2187./6784, 11./84, 0.};
    static const double b_hat[7] = {1951./21600, 0., 22642./50085, 451./720,
                                    -12231./42400, 649./6300, 1./60};
    static const double c_mid[7] = {
        6025192743./30085553152./2, 0., 51252292925./65400821598./2,
        -2691868925./45128329728./2, 187940372067./1594534317056./2,
        -1776094331./19743644256./2, 11237099./235043384./2};
    double P[8][8] = {{0}};
    P[1][0] = 1.0;
    for (int s = 2; s <= 7; s++) {
        P[s][0] = 1.0;
        for (int l = 1; l < s; l++) {
            double bl = beta[s-2][l-1];
            for (int d = 0; d < 7; d++) P[s][d+1] += bl * P[l][d];
        }
    }
    double R[8] = {0}, E[8] = {0}, M[8] = {0}, WR[8] = {0};
    R[0] = 1.0; M[0] = 1.0;
    for (int s = 1; s <= 7; s++)
        for (int d = 0; d < 7; d++) {
            R[d+1] += c_sol[s-1] * P[s][d];
            E[d+1] += (c_sol[s-1] - b_hat[s-1]) * P[s][d];
            M[d+1] += c_mid[s-1] * P[s][d];
        }
    for (int d = 0; d < 7; d++) WR[d+1] = R[d];
    Coefs c;
    for (int d = 0; d < 8; d++) {
        double W = (d == 1) ? 1.0 : 0.0, I0 = (d == 0) ? 1.0 : 0.0;
        c.r[d] = (float)R[d];
        c.e[d] = (float)E[d];
        c.pa[d] = (float)(-2*W + 2*WR[d] -  8*I0 -  8*R[d] + 16*M[d]);
        c.pb[d] = (float)( 5*W - 3*WR[d] + 18*I0 + 14*R[d] - 32*M[d]);
        c.pc[d] = (float)(-4*W + 1*WR[d] - 11*I0 -  5*R[d] + 16*M[d]);
    }
    return c;
}

// ---------------------------------------------------------------------------
// 64x64 fp32 matmul on LDS operands (256 thr, 4x4 tile per thread).
// ---------------------------------------------------------------------------
__device__ __forceinline__ void mm64(const float* __restrict__ a,
                                     const float* __restrict__ b,
                                     float* __restrict__ dst, int ty, int tx) {
    float acc[4][4];
#pragma unroll
    for (int i = 0; i < 4; i++)
#pragma unroll
        for (int j = 0; j < 4; j++) acc[i][j] = 0.f;
    for (int k = 0; k < 64; k++) {
        float av[4];
#pragma unroll
        for (int i = 0; i < 4; i++) av[i] = a[(4*ty+i)*64 + k];
        const float4 bq = *(const float4*)&b[k*64 + 4*tx];
        float bv[4] = {bq.x, bq.y, bq.z, bq.w};
#pragma unroll
        for (int i = 0; i < 4; i++)
#pragma unroll
            for (int j = 0; j < 4; j++) acc[i][j] += av[i]*bv[j];
    }
#pragma unroll
    for (int i = 0; i < 4; i++)
#pragma unroll
        for (int j = 0; j < 4; j++) dst[(4*ty+i)*64 + 4*tx + j] = acc[i][j];
}

// ---------------------------------------------------------------------------
__global__ __launch_bounds__(64) void k_zero(float* __restrict__ ws) {
    int t = threadIdx.x;
    if (t < 32) ws[OFF_CTRL + t] = 0.f;
}

// Build symmetric A from tril params; A^0..A^7 into ws; Phi slot0 = (I,0).
__global__ __launch_bounds__(256) void k_prep(const float* __restrict__ tri,
                                              float* __restrict__ ws) {
    __shared__ float sA[HH], sB[HH], sC[HH];
    const int tid = threadIdx.x;
    for (int l = tid; l < HH; l += 256) {
        int r = l >> 6, c = l & 63;
        int i = r > c ? r : c, j = r > c ? c : r;
        sA[l] = tri[(i*(i+1))/2 + j];          // tril_indices: idx(r,c)=r(r+1)/2+c
        float id = (r == c) ? 1.f : 0.f;
        ws[OFF_A + l] = id;                    // A^0 = I
        ws[OFF_PHI + l] = id;                  // Phi0 re = I
        ws[OFF_PHI + HH + l] = 0.f;            // Phi0 im = 0
    }
    __syncthreads();
    for (int l = tid; l < HH; l += 256) ws[OFF_A + HH + l] = sA[l];  // A^1
    const int ty = tid >> 4, tx = tid & 15;
    float* bufs[2] = {sB, sC};
    float* cur = sA;
    for (int d = 2; d <= 7; d++) {
        float* dst = bufs[d & 1];
        mm64(cur, sA, dst, ty, tx);
        __syncthreads();
        for (int l = tid; l < HH; l += 256) ws[OFF_A + d*HH + l] = dst[l];
        __syncthreads();
        cur = dst;
    }
}

// ---------------------------------------------------------------------------
// Init: y0 dense (u=x, v=0) into buf0; norms for Hairer initial-step:
// d0^2 = sum (x/(atol+rtol|x|))^2 ; d1^2 = sum (xA/atol)^2 ;
// d2^2 = sum (xA^2/(atol+rtol|x|))^2   (h0 cancels in jax's d2).
// ---------------------------------------------------------------------------
__global__ __launch_bounds__(256) void k_initdense(const float* __restrict__ x,
                                                   float* __restrict__ ws) {
    __shared__ float xs[64*68];
    __shared__ float m1[HH], m2[HH];
    __shared__ float red[256];
    const int tid = threadIdx.x;
    const int r0 = blockIdx.x * 64;
    const float4* xg = (const float4*)(x + (size_t)r0*64);
    for (int q = tid; q < 1024; q += 256) {
        float4 vv = xg[q];
        *(float4*)&xs[(q>>4)*68 + (q&15)*4] = vv;
    }
    for (int q = tid; q < 1024; q += 256) {
        ((float4*)m1)[q] = ((const float4*)(ws + OFF_A + HH))[q];
        ((float4*)m2)[q] = ((const float4*)(ws + OFF_A + 2*HH))[q];
    }
    __syncthreads();
    const int ty = tid >> 4, tx = tid & 15;
    float a1[4][4], a2[4][4];
#pragma unroll
    for (int i = 0; i < 4; i++)
#pragma unroll
        for (int j = 0; j < 4; j++) { a1[i][j] = 0.f; a2[i][j] = 0.f; }
    for (int k = 0; k < 64; k++) {
        float xv[4];
#pragma unroll
        for (int i = 0; i < 4; i++) xv[i] = xs[(4*ty+i)*68 + k];
        const float4 b1 = *(const float4*)&m1[k*64 + 4*tx];
        const float4 b2 = *(const float4*)&m2[k*64 + 4*tx];
        float bv1[4] = {b1.x, b1.y, b1.z, b1.w};
        float bv2[4] = {b2.x, b2.y, b2.z, b2.w};
#pragma unroll
        for (int i = 0; i < 4; i++)
#pragma unroll
            for (int j = 0; j < 4; j++) {
                a1[i][j] += xv[i]*bv1[j];
                a2[i][j] += xv[i]*bv2[j];
            }
    }
    float s0 = 0.f, s1 = 0.f, s2 = 0.f;
#pragma unroll
    for (int i = 0; i < 4; i++)
#pragma unroll
        for (int j = 0; j < 4; j++) {
            int rr = 4*ty + i, cc = 4*tx + j;
            float xval = xs[rr*68 + cc];
            float sc = 1e-3f * (1.f + fabsf(xval));
            float t0 = xval / sc;      s0 += t0*t0;
            float t1 = a1[i][j] * 1e3f; s1 += t1*t1;
            float t2 = a2[i][j] / sc;  s2 += t2*t2;
            size_t off = (size_t)(r0 + rr)*64 + cc;
            ws[OFF_Y + off] = xval;            // u0, buf0
            ws[OFF_Y + 262144 + off] = 0.f;    // v0, buf0
        }
    float sums[3] = {s0, s1, s2};
    for (int q = 0; q < 3; q++) {
        red[tid] = sums[q];
        __syncthreads();
        for (int w = 128; w > 0; w >>= 1) {
            if (tid < w) red[tid] += red[tid + w];
            __syncthreads();
        }
        if (tid == 0) atomicAdd(&ws[OFF_CTRL + 10 + q], red[0]);
        __syncthreads();
    }
}

// Hairer initial step (jax initial_step_size, order=4) + controller state.
__global__ void k_initctrl(float* __restrict__ ws) {
    float d0 = sqrtf(ws[OFF_CTRL+10]);
    float d1 = sqrtf(ws[OFF_CTRL+11]);
    float d2 = sqrtf(ws[OFF_CTRL+12]);
    float h0 = ((d0 < 1e-5f) || (d1 < 1e-5f)) ? 1e-6f : 0.01f*d0/d1;
    float h1;
    if ((d1 <= 1e-15f) && (d2 <= 1e-15f)) h1 = fmaxf(1e-6f, h0*1e-3f);
    else h1 = powf(0.01f / fmaxf(d1, d2), 0.2f);
    float dt = fminf(100.f*h0, h1);
    float* cf = ws + OFF_CTRL;
    int* ci = (int*)cf;
    cf[0] = 1.0f;   // t
    cf[1] = dt;     // h
    cf[2] = 2.0f;   // next target
    ci[4] = 0;      // na (accepted count / current Phi slot)
    ci[5] = 0;      // attempts
    ci[6] = 0;      // done
    ci[7] = 0;      // ybuf
    ci[8] = 1;      // target idx
    float* rc = ws + OFF_REC;   // target 0 = y0: step 0, tau 0
    rc[0] = 0.f; rc[1] = 0.f; rc[2] = 1.f; rc[3] = 0.f;
}

// Weighted sums: Rre/Rim/Ere/Eim = sum_d coef_d h^d i^d A^d
__device__ void compute_sums(float* __restrict__ ws, const Coefs& C, float h,
                             int tid) {
    float hp[8];
    hp[0] = 1.f;
#pragma unroll
    for (int d = 1; d < 8; d++) hp[d] = hp[d-1]*h;
    for (int e = tid; e < HH; e += 256) {
        float rre = 0.f, rim = 0.f, ere = 0.f, eim = 0.f;
#pragma unroll
        for (int d = 0; d < 8; d++) {
            float ad = ws[OFF_A + d*HH + e];
            float wr = C.r[d]*hp[d], we = C.e[d]*hp[d];
            int m = d & 3;
            if (m == 0)      { rre += wr*ad; ere += we*ad; }
            else if (m == 1) { rim += wr*ad; eim += we*ad; }
            else if (m == 2) { rre -= wr*ad; ere -= we*ad; }
            else             { rim -= wr*ad; eim -= we*ad; }
        }
        ws[OFF_RE + e] = rre;
        ws[OFF_RE + HH + e] = rim;
        ws[OFF_RE + 2*HH + e] = ere;
        ws[OFF_RE + 3*HH + e] = eim;
    }
}

// ---------------------------------------------------------------------------
// The integrator: cooperative, 64 blocks x 256. Per attempt:
//  small(16 blk): Phi1 = Phi*R, EY = Phi*E (complex 64x64)
//  dense(64 blk): y1 = x_rows*Phi1, err = x_rows*EY, ratio^2 sum, store y1
//  ctrl (blk 0) : mer -> accept/step-size (jax optimal_step_size), record
//                 integer targets with (Phi slot, tau, h), next R/E sums.
// ---------------------------------------------------------------------------
__global__ __launch_bounds__(256) void k_integrate(const float* __restrict__ x,
                                                   float* __restrict__ ws,
                                                   Coefs C) {
    __shared__ float xs[64*68];
    __shared__ float mats[4*HH];
    __shared__ float red[256];
    __shared__ float sh_h;
    __shared__ int sh_done;
    cg::grid_group grid = cg::this_grid();
    const int tid = threadIdx.x;
    const int bid = blockIdx.x;
    const int ty = tid >> 4, tx = tid & 15;
    volatile float* cf = ws + OFF_CTRL;
    volatile int* ci = (volatile int*)(ws + OFF_CTRL);

    const int r0 = bid * 64;
    const float4* xg = (const float4*)(x + (size_t)r0*64);
    for (int q = tid; q < 1024; q += 256) {
        float4 vv = xg[q];
        *(float4*)&xs[(q>>4)*68 + (q&15)*4] = vv;
    }
    if (bid == 0) compute_sums(ws, C, cf[1], tid);
    grid.sync();

    for (int iter = 0; iter < MAXATT; iter++) {
        const int na = ci[4];
        // ---- phase small ----
        if (bid < 16) {
            const int o = bid & 3;
            const int slab = (bid >> 2) * 16;
            const float* Pre = ws + OFF_PHI + (size_t)na*8192;
            const float* Pim = Pre + HH;
            const float* Rre = ws + OFF_RE;
            const float* Rim = Rre + HH;
            const float* Ere = Rre + 2*HH;
            const float* Eim = Rre + 3*HH;
            const float *B1, *B2;
            float sgn;
            if (o == 0)      { B1 = Rre; B2 = Rim; sgn = -1.f; }
            else if (o == 1) { B1 = Rim; B2 = Rre; sgn =  1.f; }
            else if (o == 2) { B1 = Ere; B2 = Eim; sgn = -1.f; }
            else             { B1 = Eim; B2 = Ere; sgn =  1.f; }
            float* sa1 = mats;
            float* sa2 = mats + 1024;
            float* sb1 = mats + 2048;
            float* sb2 = mats + 2048 + HH;
            for (int q = tid; q < 1024; q += 256) {
                sa1[q] = Pre[slab*64 + q];
                sa2[q] = Pim[slab*64 + q];
            }
            for (int q = tid; q < HH; q += 256) { sb1[q] = B1[q]; sb2[q] = B2[q]; }
            __syncthreads();
            float* dst;
            if (o == 0)      dst = ws + OFF_PHI + (size_t)(na+1)*8192;
            else if (o == 1) dst = ws + OFF_PHI + (size_t)(na+1)*8192 + HH;
            else if (o == 2) dst = ws + OFF_EY;
            else             dst = ws + OFF_EY + HH;
            for (int e = tid; e < 1024; e += 256) {
                int rr = e >> 6, cc = e & 63;
                float acc = 0.f;
                for (int k = 0; k < 64; k++)
                    acc += sa1[rr*64+k]*sb1[k*64+cc] + sgn*sa2[rr*64+k]*sb2[k*64+cc];
                dst[(size_t)(slab+rr)*64 + cc] = acc;
            }
        }
        grid.sync();
        // ---- phase dense ----
        {
            const int ybuf = ci[7];
            const float* P1re = ws + OFF_PHI + (size_t)(na+1)*8192;
            for (int q = tid; q < 1024; q += 256) {
                ((float4*)mats)[q]          = ((const float4*)P1re)[q];
                ((float4*)(mats + HH))[q]   = ((const float4*)(P1re + HH))[q];
                ((float4*)(mats + 2*HH))[q] = ((const float4*)(ws + OFF_EY))[q];
                ((float4*)(mats + 3*HH))[q] = ((const float4*)(ws + OFF_EY + HH))[q];
            }
            __syncthreads();
            float au[4][4], av_[4][4], ae[4][4], af_[4][4];
#pragma unroll
            for (int i = 0; i < 4; i++)
#pragma unroll
                for (int j = 0; j < 4; j++) {
                    au[i][j] = 0.f; av_[i][j] = 0.f; ae[i][j] = 0.f; af_[i][j] = 0.f;
                }
            for (int k = 0; k < 64; k++) {
                float xv[4];
#pragma unroll
                for (int i = 0; i < 4; i++) xv[i] = xs[(4*ty+i)*68 + k];
                const float4 b0 = *(const float4*)&mats[k*64 + 4*tx];
                const float4 b1 = *(const float4*)&mats[HH + k*64 + 4*tx];
                const float4 b2 = *(const float4*)&mats[2*HH + k*64 + 4*tx];
                const float4 b3 = *(const float4*)&mats[3*HH + k*64 + 4*tx];
                float v0[4] = {b0.x, b0.y, b0.z, b0.w};
                float v1[4] = {b1.x, b1.y, b1.z, b1.w};
                float v2[4] = {b2.x, b2.y, b2.z, b2.w};
                float v3[4] = {b3.x, b3.y, b3.z, b3.w};
#pragma unroll
                for (int i = 0; i < 4; i++)
#pragma unroll
                    for (int j = 0; j < 4; j++) {
                        au[i][j]  += xv[i]*v0[j];
                        av_[i][j] += xv[i]*v1[j];
                        ae[i][j]  += xv[i]*v2[j];
                        af_[i][j] += xv[i]*v3[j];
                    }
            }
            const float* yu0 = ws + OFF_Y + (size_t)ybuf*524288;
            const float* yv0 = yu0 + 262144;
            float* yu1 = ws + OFF_Y + (size_t)(1-ybuf)*524288;
            float* yv1 = yu1 + 262144;
            float s = 0.f;
#pragma unroll
            for (int i = 0; i < 4; i++)
#pragma unroll
                for (int j = 0; j < 4; j++) {
                    size_t off = (size_t)(r0 + 4*ty + i)*64 + (4*tx + j);
                    float u1 = au[i][j], v1 = av_[i][j];
                    float u0 = yu0[off], v0 = yv0[off];
                    float tu = 1e-3f + 1e-3f*fmaxf(fabsf(u0), fabsf(u1));
                    float tv = 1e-3f + 1e-3f*fmaxf(fabsf(v0), fabsf(v1));
                    float ru = ae[i][j]/tu, rv = af_[i][j]/tv;
                    s += ru*ru + rv*rv;
                    yu1[off] = u1;
                    yv1[off] = v1;
                }
            red[tid] = s;
            __syncthreads();
            for (int w = 128; w > 0; w >>= 1) {
                if (tid < w) red[tid] += red[tid + w];
                __syncthreads();
            }
            if (tid == 0) ws[OFF_PART + bid] = red[0];
        }
        grid.sync();
        // ---- phase ctrl ----
        if (bid == 0) {
            if (tid == 0) {
                float S = 0.f;
                for (int q = 0; q < 64; q++) S += ws[OFF_PART + q];
                float mer = S / 524288.f;           // mean over raveled (u,v)
                float t = cf[0], h = cf[1], ntgt = cf[2];
                int nna = ci[4], att = ci[5], done = ci[6];
                int ybuf = ci[7], tgi = ci[8];
                bool acc = (mer <= 1.0f);
                float fac = 0.9f * powf(sqrtf(mer), -0.2f);   // safety*rms^{-1/5}
                float lo = acc ? 1.0f : 0.2f;                 // dfactor
                fac = fminf(10.0f, fmaxf(fac, lo));           // ifactor
                float hnew = h * fac;
                if (acc) {
                    float tnew = t + h;                        // fp32, as jax
                    int step0 = nna;
                    nna += 1;
                    ybuf ^= 1;
                    while (tgi < 128 && ntgt <= tnew) {
                        float tau = (ntgt - t) / (tnew - t);
                        float* rc = ws + OFF_REC + 4*tgi;
                        rc[0] = (float)step0; rc[1] = tau; rc[2] = h;
                        ntgt += 1.0f;
                        tgi++;
                    }
                    t = tnew;
                    if (tgi >= 128) done = 1;
                }
                att++;
                if (att >= MAXATT || nna + 1 >= NSLOT) done = 1;
                cf[0] = t; cf[1] = hnew; cf[2] = ntgt;
                ci[4] = nna; ci[5] = att; ci[6] = done;
                ci[7] = ybuf; ci[8] = tgi;
                sh_h = hnew;
                sh_done = done;
            }
            __syncthreads();
            if (!sh_done) compute_sums(ws, C, sh_h, tid);
        }
        grid.sync();
        if (((volatile int*)(ws + OFF_CTRL))[6]) break;
    }
}

// Theta_t = Phi_step * (tau^4 Pa + tau^3 Pb + tau^2 Pc + tau W + 1)(W), Re only.
__global__ __launch_bounds__(256) void k_make_theta(float* __restrict__ ws,
                                                    Coefs C) {
    __shared__ float sre[HH], simm[HH], pre[HH], pim[HH];
    const int tid = threadIdx.x;
    const int t = blockIdx.x;
    const float* rc = ws + OFF_REC + 4*t;
    int step = (int)rc[0];
    if (step < 0) step = 0;
    if (step >= NSLOT) step = NSLOT - 1;
    const float tau = rc[1], h = rc[2];
    float hp[8];
    hp[0] = 1.f;
#pragma unroll
    for (int d = 1; d < 8; d++) hp[d] = hp[d-1]*h;
    float t2 = tau*tau, t3 = t2*tau, t4 = t3*tau;
    float wre[8], wim[8];
#pragma unroll
    for (int d = 0; d < 8; d++) {
        float sd = t4*C.pa[d] + t3*C.pb[d] + t2*C.pc[d];
        if (d == 1) sd += tau;
        if (d == 0) sd += 1.f;
        float w = sd * hp[d];
        int m = d & 3;
        wre[d] = (m == 0) ? w : (m == 2 ? -w : 0.f);
        wim[d] = (m == 1) ? w : (m == 3 ? -w : 0.f);
    }
    const float* phre = ws + OFF_PHI + (size_t)step*8192;
    const float* phim = phre + HH;
    for (int e = tid; e < HH; e += 256) {
        float are = 0.f, aim = 0.f;
#pragma unroll
        for (int d = 0; d < 8; d++) {
            float ad = ws[OFF_A + d*HH + e];
            are += wre[d]*ad;
            aim += wim[d]*ad;
        }
        sre[e] = are;
        simm[e] = aim;
        pre[e] = phre[e];
        pim[e] = phim[e];
    }
    __syncthreads();
    for (int e = tid; e < HH; e += 256) {
        int rr = e >> 6, cc = e & 63;
        float acc = 0.f;
        for (int k = 0; k < 64; k++)
            acc += pre[rr*64+k]*sre[k*64+cc] - pim[rr*64+k]*simm[k*64+cc];
        ws[OFF_THETA + (size_t)t*HH + e] = acc;
    }
}

// out[b, t, :] = x[b, :] @ Theta_t   (128 rows x one t per block)
__global__ __launch_bounds__(256) void k_out(const float* __restrict__ x,
                                             const float* __restrict__ ws,
                                             float* __restrict__ out) {
    __shared__ float xs[128*68];
    __shared__ float ct[HH];
    const int tid = threadIdx.x;
    const int b0 = blockIdx.x * 128;
    const int t = blockIdx.y;
    const float4* xg4 = (const float4*)(x + (size_t)b0*64);
    for (int i4 = tid; i4 < 2048; i4 += 256) {
        float4 vv = xg4[i4];
        *(float4*)&xs[(i4>>4)*68 + (i4&15)*4] = vv;
    }
    const float4* cg4 = (const float4*)(ws + OFF_THETA + (size_t)t*HH);
    for (int i4 = tid; i4 < 1024; i4 += 256) ((float4*)ct)[i4] = cg4[i4];
    __syncthreads();
    const int ty = tid >> 4, tx = tid & 15;
    float acc[8][4];
#pragma unroll
    for (int i = 0; i < 8; i++)
#pragma unroll
        for (int c = 0; c < 4; c++) acc[i][c] = 0.f;
    for (int kg = 0; kg < 16; kg++) {
        const int k0 = kg*4;
        float av[8][4];
#pragma unroll
        for (int i = 0; i < 8; i++) {
            float4 tq = *(const float4*)&xs[(ty + 16*i)*68 + k0];
            av[i][0] = tq.x; av[i][1] = tq.y; av[i][2] = tq.z; av[i][3] = tq.w;
        }
        float bv[4][4];
#pragma unroll
        for (int kk = 0; kk < 4; kk++) {
            float4 tq = *(const float4*)&ct[(k0+kk)*64 + 4*tx];
            bv[kk][0] = tq.x; bv[kk][1] = tq.y; bv[kk][2] = tq.z; bv[kk][3] = tq.w;
        }
#pragma unroll
        for (int i = 0; i < 8; i++)
#pragma unroll
            for (int c = 0; c < 4; c++)
#pragma unroll
                for (int kk = 0; kk < 4; kk++)
                    acc[i][c] += av[i][kk]*bv[kk][c];
    }
#pragma unroll
    for (int i = 0; i < 8; i++) {
        int row = b0 + ty + 16*i;
        size_t off = ((size_t)row*128 + t)*64 + 4*tx;
        float4 vv = {acc[i][0], acc[i][1], acc[i][2], acc[i][3]};
        *(float4*)&out[off] = vv;
    }
}

extern "C" void kernel_launch(void* const* d_in, const int* in_sizes, int n_in,
                              void* d_out, int out_size, void* d_ws, size_t ws_size,
                              hipStream_t stream) {
    const float* x = (const float*)d_in[0];
    const float* tri = (const float*)d_in[1];
    float* out = (float*)d_out;
    float* ws = (float*)d_ws;
    Coefs C = make_coefs();

    hipLaunchKernelGGL(k_zero, dim3(1), dim3(64), 0, stream, ws);
    hipLaunchKernelGGL(k_prep, dim3(1), dim3(256), 0, stream, tri, ws);
    hipLaunchKernelGGL(k_initdense, dim3(64), dim3(256), 0, stream, x, ws);
    hipLaunchKernelGGL(k_initctrl, dim3(1), dim3(1), 0, stream, ws);
    void* args[3] = {(void*)&x, (void*)&ws, (void*)&C};
    hipLaunchCooperativeKernel((void*)k_integrate, dim3(64), dim3(256), args, 0,
                               stream);
    hipLaunchKernelGGL(k_make_theta, dim3(128), dim3(256), 0, stream, ws, C);
    hipLaunchKernelGGL(k_out, dim3(32, 128), dim3(256), 0, stream, x, ws, out);
}